// Round 2
// baseline (414.192 us; speedup 1.0000x reference)
//
#include <hip/hip_runtime.h>
#include <stdint.h>

// ---------------- common types / helpers ----------------
typedef _Float16 f16x8 __attribute__((ext_vector_type(8)));
typedef _Float16 f16x4 __attribute__((ext_vector_type(4)));
typedef float f32x4  __attribute__((ext_vector_type(4)));

__device__ __forceinline__ _Float16 f2h(float f){ return (_Float16)f; }

// Problem constants
#define NB   32
#define NC   512
#define NH   8
#define ND   64
#define NN   1024

// ---------------- prep kernels ----------------
__global__ __launch_bounds__(256) void wt_conv(const float* __restrict__ Wq,
                                               const float* __restrict__ Wk,
                                               const float* __restrict__ Wv,
                                               _Float16* __restrict__ Wt){
  int idx = blockIdx.x * 256 + threadIdx.x;          // 1536*512 = 786432 exact
  int sel = idx >> 18;                               // 262144 per matrix
  const float* W = (sel == 0) ? Wq : (sel == 1) ? Wk : Wv;
  Wt[idx] = f2h(W[idx & 262143]);
}

__global__ __launch_bounds__(256) void transpose_x(const float* __restrict__ x,
                                                   _Float16* __restrict__ xT){
  __shared__ float tile[32][33];
  int n0 = blockIdx.x * 32, c0 = blockIdx.y * 32, b = blockIdx.z;
  int t = threadIdx.x;
  int tn = t & 31, tc = t >> 5;                      // 8 c-rows per pass
#pragma unroll
  for (int k = 0; k < 4; k++)
    tile[tc + 8*k][tn] = x[(b*NC + c0 + tc + 8*k)*NN + n0 + tn];
  __syncthreads();
#pragma unroll
  for (int k = 0; k < 4; k++)
    xT[(b*NN + n0 + tc + 8*k)*NC + c0 + tn] = f2h(tile[tn][tc + 8*k]);
}

__global__ __launch_bounds__(256) void pos_conv(const float* __restrict__ rel_h,
                                                const float* __restrict__ rel_w,
                                                _Float16* __restrict__ pos_t){
  int idx = blockIdx.x * 256 + threadIdx.x;          // 8*1024*64 = 524288 exact
  int d = idx & 63, n = (idx >> 6) & 1023, h = idx >> 16;
  int ww = n >> 5, hh = n & 31;
  float v = rel_h[(h*ND + d)*32 + hh] + rel_w[(h*ND + d)*32 + ww];
  pos_t[idx] = f2h(v);
}

// ---------------- QKV projection GEMM ----------------
// C[o,pix] = sum_c Wt[o,c]*xT[b,pix,c] + bias[o], o in [0,1536) stacked q|k|v.
// Output: q/k/v_ws pixel-major f16 [b][h][pix][d].
#define ASTR 72      // LDS K-stride in halves (64 + 8 pad) -> 144B
#define TSTR 136     // epilogue tile stride in halves (128 + 8) -> 272B

__global__ __launch_bounds__(256) void proj_gemm(const _Float16* __restrict__ Wt,
                                                 const _Float16* __restrict__ xT,
                                                 const float* __restrict__ bq,
                                                 const float* __restrict__ bk,
                                                 const float* __restrict__ bv,
                                                 _Float16* __restrict__ q_ws,
                                                 _Float16* __restrict__ k_ws,
                                                 _Float16* __restrict__ v_ws){
  __shared__ _Float16 smem[2 * 128 * ASTR];          // 18432 halves = 36864 B
  _Float16* As = smem;                               // [128][ASTR]
  _Float16* Bs = smem + 128 * ASTR;                  // [128][ASTR]

  int mt = blockIdx.x;         // 0..11  (row tile of 1536)
  int nt = blockIdx.y;         // 0..7   (pixel tile of 1024)
  int b  = blockIdx.z;
  int t = threadIdx.x, lane = t & 63, w = t >> 6;
  int wm = w >> 1, wn = w & 1;
  int lr = lane & 15, lg = lane >> 4;

  f32x4 acc[4][4];
#pragma unroll
  for (int i = 0; i < 4; i++)
#pragma unroll
    for (int j = 0; j < 4; j++) acc[i][j] = (f32x4)0.f;

  const _Float16* Arow = Wt + mt * 128 * NC;
  const _Float16* Brow = xT + (b * NN + nt * 128) * NC;

  for (int k0 = 0; k0 < NC; k0 += 64){
    __syncthreads();
#pragma unroll
    for (int i = 0; i < 4; i++){
      int lin = t + 256 * i;                          // 0..1023
      int row = lin >> 3, c8 = lin & 7;
      *(f16x8*)(As + row*ASTR + c8*8) = *(const f16x8*)(Arow + row*NC + k0 + c8*8);
      *(f16x8*)(Bs + row*ASTR + c8*8) = *(const f16x8*)(Brow + row*NC + k0 + c8*8);
    }
    __syncthreads();
#pragma unroll
    for (int ks = 0; ks < 2; ks++){
      f16x8 af[4], bfr[4];
#pragma unroll
      for (int mi = 0; mi < 4; mi++)
        af[mi] = *(f16x8*)(As + (wm*64 + mi*16 + lr)*ASTR + ks*32 + lg*8);
#pragma unroll
      for (int nj = 0; nj < 4; nj++)
        bfr[nj] = *(f16x8*)(Bs + (wn*64 + nj*16 + lr)*ASTR + ks*32 + lg*8);
#pragma unroll
      for (int mi = 0; mi < 4; mi++)
#pragma unroll
        for (int nj = 0; nj < 4; nj++)
          acc[mi][nj] = __builtin_amdgcn_mfma_f32_16x16x32_f16(af[mi], bfr[nj], acc[mi][nj], 0, 0, 0);
    }
  }
  __syncthreads();

  // epilogue: +bias, ->f16, LDS tile [pix][o_loc] (TSTR), then coalesced store
  _Float16* Ts = smem;                                // 128*136 = 17408 halves, fits
#pragma unroll
  for (int mi = 0; mi < 4; mi++){
    int o0 = wm*64 + mi*16 + 4*lg;
    int og = mt*128 + o0;
    int sel = og >> 9, oo = og & 511;
    const float* bias = (sel == 0) ? bq : (sel == 1) ? bk : bv;
    float b0 = bias[oo], b1 = bias[oo+1], b2 = bias[oo+2], b3 = bias[oo+3];
#pragma unroll
    for (int nj = 0; nj < 4; nj++){
      int pix = wn*64 + nj*16 + lr;
      f16x4 pk;
      pk[0] = f2h(acc[mi][nj][0] + b0);
      pk[1] = f2h(acc[mi][nj][1] + b1);
      pk[2] = f2h(acc[mi][nj][2] + b2);
      pk[3] = f2h(acc[mi][nj][3] + b3);
      *(f16x4*)(Ts + pix*TSTR + o0) = pk;
    }
  }
  __syncthreads();
#pragma unroll
  for (int i = 0; i < 8; i++){
    int lin = t + 256 * i;                            // 0..2047
    int c_o = lin & 15, pix = lin >> 4;
    f16x8 v = *(f16x8*)(Ts + pix*TSTR + c_o*8);
    int og = mt*128 + c_o*8;
    int sel = og >> 9, oo = og & 511;
    int head = oo >> 6, d = oo & 63;
    _Float16* dst = (sel == 0) ? q_ws : (sel == 1) ? k_ws : v_ws;
    *(f16x8*)(dst + (((b*NH + head)*NN) + nt*128 + pix)*ND + d) = v;
  }
}

// ---------------- fused attention ----------------
// Block: (qtile of 128, head, batch). KT=64 keys/tile, Deff=128.
// LDS (halves): Qc[128][136] @0 | KcP @17408 (Kc[64][136] aliased with P[128][72]) | Vt @26624 (64 rows x 72, XOR-swizzled)
#define QSTR 136
#define PSTR 72
#define VSTR 72
#define OSTR 65
#define LDS_KCP 17408
#define LDS_VT  26624

__global__ __launch_bounds__(256) void attn_kernel(const _Float16* __restrict__ q_ws,
                                                   const _Float16* __restrict__ k_ws,
                                                   const _Float16* __restrict__ v_ws,
                                                   const _Float16* __restrict__ pos_t,
                                                   float* __restrict__ out){
  __shared__ _Float16 smem[31232];                   // 62464 B
  _Float16* Qc  = smem;
  _Float16* KcP = smem + LDS_KCP;
  _Float16* Vt  = smem + LDS_VT;

  int qt = blockIdx.x, h = blockIdx.y, b = blockIdx.z;
  int t = threadIdx.x, lane = t & 63, w = t >> 6;    // wave w owns q rows [w*32, w*32+32)
  int lr = lane & 15, lg = lane >> 4;

  const _Float16* qbh = q_ws + (b*NH + h) * NN * ND;
  const _Float16* kbh = k_ws + (b*NH + h) * NN * ND;
  const _Float16* vbh = v_ws + (b*NH + h) * NN * ND;
  const _Float16* pph = pos_t + h * NN * ND;

  // stage Qc: row j -> [ q(64) | pos(64) ]
#pragma unroll
  for (int i = 0; i < 8; i++){
    int lin = t + 256*i;                             // 0..2047
    int row = lin >> 4, c8 = lin & 15;
    const _Float16* src = (c8 < 8) ? (qbh + (qt*128 + row)*ND + c8*8)
                                   : (pph + (qt*128 + row)*ND + (c8 - 8)*8);
    *(f16x8*)(Qc + row*QSTR + c8*8) = *(const f16x8*)src;
  }

  float m_r[2][4], l_r[2][4];
  f32x4 oacc[2][4];
#pragma unroll
  for (int qi = 0; qi < 2; qi++)
#pragma unroll
    for (int r = 0; r < 4; r++){ m_r[qi][r] = -1e30f; l_r[qi][r] = 0.f; }
#pragma unroll
  for (int qi = 0; qi < 2; qi++)
#pragma unroll
    for (int dj = 0; dj < 4; dj++) oacc[qi][dj] = (f32x4)0.f;

  for (int n0 = 0; n0 < NN; n0 += 64){
    __syncthreads();
    // stage Kc: row n -> [ k(64) | q(64) ]
#pragma unroll
    for (int i = 0; i < 4; i++){
      int lin = t + 256*i;                           // 0..1023
      int row = lin >> 4, c8 = lin & 15;
      const _Float16* src = (c8 < 8) ? (kbh + (n0 + row)*ND + c8*8)
                                     : (qbh + (n0 + row)*ND + (c8 - 8)*8);
      *(f16x8*)(KcP + row*QSTR + c8*8) = *(const f16x8*)src;
    }
    // stage Vt transposed with XOR swizzle: Vt[d][n ^ ((d>>3)<<3)]
#pragma unroll
    for (int i = 0; i < 2; i++){
      int lin = t + 256*i;                           // 0..511
      int n = lin >> 3, d0 = lin & 7;
      f16x8 vv = *(const f16x8*)(vbh + (n0 + n)*ND + d0*8);
      int nswz = n ^ (d0 << 3);
#pragma unroll
      for (int e = 0; e < 8; e++) Vt[(d0*8 + e)*VSTR + nswz] = vv[e];
    }
    __syncthreads();

    // S = Qc(rows of this wave) . Kc^T   [32 x 64], K=128
    f32x4 sacc[2][4];
#pragma unroll
    for (int qi = 0; qi < 2; qi++)
#pragma unroll
      for (int nj = 0; nj < 4; nj++) sacc[qi][nj] = (f32x4)0.f;
#pragma unroll
    for (int ks = 0; ks < 4; ks++){
      f16x8 aq[2], bk_[4];
#pragma unroll
      for (int qi = 0; qi < 2; qi++)
        aq[qi] = *(f16x8*)(Qc + (w*32 + qi*16 + lr)*QSTR + ks*32 + lg*8);
#pragma unroll
      for (int nj = 0; nj < 4; nj++)
        bk_[nj] = *(f16x8*)(KcP + (nj*16 + lr)*QSTR + ks*32 + lg*8);
#pragma unroll
      for (int qi = 0; qi < 2; qi++)
#pragma unroll
        for (int nj = 0; nj < 4; nj++)
          sacc[qi][nj] = __builtin_amdgcn_mfma_f32_16x16x32_f16(aq[qi], bk_[nj], sacc[qi][nj], 0, 0, 0);
    }

    // online softmax (registers only)
    float ps[2][4][4];  // [qi][r][nj]
#pragma unroll
    for (int qi = 0; qi < 2; qi++)
#pragma unroll
      for (int r = 0; r < 4; r++){
        float mx = fmaxf(fmaxf(sacc[qi][0][r], sacc[qi][1][r]), fmaxf(sacc[qi][2][r], sacc[qi][3][r]));
        mx = fmaxf(mx, __shfl_xor(mx, 1));
        mx = fmaxf(mx, __shfl_xor(mx, 2));
        mx = fmaxf(mx, __shfl_xor(mx, 4));
        mx = fmaxf(mx, __shfl_xor(mx, 8));
        float mn = fmaxf(m_r[qi][r], mx);
        float cr = __expf(m_r[qi][r] - mn);
        m_r[qi][r] = mn;
        float lacc = l_r[qi][r] * cr;
#pragma unroll
        for (int nj = 0; nj < 4; nj++){
          float p = __expf(sacc[qi][nj][r] - mn);
          ps[qi][r][nj] = p; lacc += p;
        }
        l_r[qi][r] = lacc;
#pragma unroll
        for (int dj = 0; dj < 4; dj++) oacc[qi][dj][r] *= cr;
      }

    __syncthreads();   // everyone done reading Kc before P overwrites it
#pragma unroll
    for (int qi = 0; qi < 2; qi++)
#pragma unroll
      for (int r = 0; r < 4; r++)
#pragma unroll
        for (int nj = 0; nj < 4; nj++)
          KcP[(w*32 + qi*16 + 4*lg + r)*PSTR + nj*16 + lr] = f2h(ps[qi][r][nj]);
    __syncthreads();

    // PV: oacc += P . Vt   (K = 64 keys)
#pragma unroll
    for (int ks = 0; ks < 2; ks++){
      f16x8 ap[2], bv_[4];
#pragma unroll
      for (int qi = 0; qi < 2; qi++)
        ap[qi] = *(f16x8*)(KcP + (w*32 + qi*16 + lr)*PSTR + ks*32 + lg*8);
#pragma unroll
      for (int dj = 0; dj < 4; dj++){
        int d = dj*16 + lr;
        int nn = ks*32 + lg*8;
        bv_[dj] = *(f16x8*)(Vt + d*VSTR + (nn ^ ((d >> 3) << 3)));
      }
#pragma unroll
      for (int qi = 0; qi < 2; qi++)
#pragma unroll
        for (int dj = 0; dj < 4; dj++)
          oacc[qi][dj] = __builtin_amdgcn_mfma_f32_16x16x32_f16(ap[qi], bv_[dj], oacc[qi][dj], 0, 0, 0);
    }
  }

  // final 1/l
  float inv[2][4];
#pragma unroll
  for (int qi = 0; qi < 2; qi++)
#pragma unroll
    for (int r = 0; r < 4; r++){
      float s = l_r[qi][r];
      s += __shfl_xor(s, 1); s += __shfl_xor(s, 2);
      s += __shfl_xor(s, 4); s += __shfl_xor(s, 8);
      inv[qi][r] = 1.f / s;
    }

  __syncthreads();
  float* Ot = (float*)smem;                          // [128][OSTR] fp32 = 33280 B
#pragma unroll
  for (int qi = 0; qi < 2; qi++)
#pragma unroll
    for (int dj = 0; dj < 4; dj++)
#pragma unroll
      for (int r = 0; r < 4; r++)
        Ot[(w*32 + qi*16 + 4*lg + r)*OSTR + dj*16 + lr] = oacc[qi][dj][r] * inv[qi][r];
  __syncthreads();

  // coalesced store: out[b][h*64+d][qt*128 + j]
#pragma unroll
  for (int i = 0; i < 8; i++){
    int lin = t + 256*i;                             // 0..2047
    int jc = lin & 31, d = lin >> 5;
    float4 v;
    v.x = Ot[(jc*4 + 0)*OSTR + d];
    v.y = Ot[(jc*4 + 1)*OSTR + d];
    v.z = Ot[(jc*4 + 2)*OSTR + d];
    v.w = Ot[(jc*4 + 3)*OSTR + d];
    *(float4*)(out + (b*NC + h*ND + d)*NN + qt*128 + jc*4) = v;
  }
}

// ---------------- LayerNorm + residual ----------------
__global__ __launch_bounds__(256) void ln_partial(const float* __restrict__ out,
                                                  float* __restrict__ red){
  int i = blockIdx.x, b = blockIdx.y, t = threadIdx.x;
  const float4* p = (const float4*)(out + b*524288 + i*65536);
  float s = 0.f, sq = 0.f;
  for (int k = t; k < 16384; k += 256){
    float4 v = p[k];
    s  += v.x + v.y + v.z + v.w;
    sq += v.x*v.x + v.y*v.y + v.z*v.z + v.w*v.w;
  }
  for (int off = 32; off; off >>= 1){ s += __shfl_down(s, off); sq += __shfl_down(sq, off); }
  __shared__ float ls[8];
  int w = t >> 6, lane = t & 63;
  if (lane == 0){ ls[w*2] = s; ls[w*2 + 1] = sq; }
  __syncthreads();
  if (t == 0){
    red[(b*8 + i)*2]     = ls[0] + ls[2] + ls[4] + ls[6];
    red[(b*8 + i)*2 + 1] = ls[1] + ls[3] + ls[5] + ls[7];
  }
}

__global__ void ln_stats(const float* __restrict__ red, float* __restrict__ stats){
  int b = threadIdx.x;
  if (b < 32){
    float s = 0.f, sq = 0.f;
    for (int j = 0; j < 8; j++){ s += red[(b*8 + j)*2]; sq += red[(b*8 + j)*2 + 1]; }
    float mu  = s * (1.f / 524288.f);
    float var = sq * (1.f / 524288.f) - mu*mu;
    stats[b*2] = mu;
    stats[b*2 + 1] = rsqrtf(var + 1e-5f);
  }
}

__global__ __launch_bounds__(256) void ln_apply(const float* __restrict__ x,
                                                const float* __restrict__ lw,
                                                const float* __restrict__ lb,
                                                const float* __restrict__ stats,
                                                float* __restrict__ out){
  int tid = blockIdx.x*256 + threadIdx.x;
  for (int i4 = tid; i4 < 4194304; i4 += 524288){
    int b = i4 >> 17;                                // 131072 float4 per batch
    int r4 = i4 & 131071;
    float mu = stats[b*2], rs = stats[b*2 + 1];
    float4 o  = ((const float4*)out)[i4];
    float4 xv = ((const float4*)x)[i4];
    float4 ww = ((const float4*)lw)[r4];
    float4 bb = ((const float4*)lb)[r4];
    o.x = (o.x - mu)*rs*ww.x + bb.x + xv.x;
    o.y = (o.y - mu)*rs*ww.y + bb.y + xv.y;
    o.z = (o.z - mu)*rs*ww.z + bb.z + xv.z;
    o.w = (o.w - mu)*rs*ww.w + bb.w + xv.w;
    ((float4*)out)[i4] = o;
  }
}

// ---------------- launch ----------------
extern "C" void kernel_launch(void* const* d_in, const int* in_sizes, int n_in,
                              void* d_out, int out_size, void* d_ws, size_t ws_size,
                              hipStream_t stream){
  (void)in_sizes; (void)n_in; (void)out_size; (void)ws_size;
  const float* x    = (const float*)d_in[0];
  const float* Wq   = (const float*)d_in[1];
  const float* bq   = (const float*)d_in[2];
  const float* Wk   = (const float*)d_in[3];
  const float* bk   = (const float*)d_in[4];
  const float* Wv   = (const float*)d_in[5];
  const float* bv   = (const float*)d_in[6];
  const float* relh = (const float*)d_in[7];
  const float* relw = (const float*)d_in[8];
  const float* lnw  = (const float*)d_in[9];
  const float* lnb  = (const float*)d_in[10];
  float* out = (float*)d_out;
  char* ws = (char*)d_ws;

  _Float16* q_ws  = (_Float16*)(ws);
  _Float16* k_ws  = (_Float16*)(ws + 33554432);
  _Float16* v_ws  = (_Float16*)(ws + 67108864);
  _Float16* xT    = (_Float16*)(ws + 100663296);
  _Float16* Wt    = (_Float16*)(ws + 134217728);
  _Float16* pos_t = (_Float16*)(ws + 135790592);
  float* red   = (float*)(ws + 136839168);
  float* stats = red + 512;

  wt_conv    <<<3072, 256, 0, stream>>>(Wq, Wk, Wv, Wt);
  transpose_x<<<dim3(32, 16, 32), 256, 0, stream>>>(x, xT);
  pos_conv   <<<2048, 256, 0, stream>>>(relh, relw, pos_t);
  proj_gemm  <<<dim3(12, 8, 32), 256, 0, stream>>>(Wt, xT, bq, bk, bv, q_ws, k_ws, v_ws);
  attn_kernel<<<dim3(8, 8, 32), 256, 0, stream>>>(q_ws, k_ws, v_ws, pos_t, out);
  ln_partial <<<dim3(8, 32), 256, 0, stream>>>(out, red);
  ln_stats   <<<1, 64, 0, stream>>>(red, stats);
  ln_apply   <<<2048, 256, 0, stream>>>(x, lnw, lnb, stats, out);
}

// Round 3
// 319.533 us; speedup vs baseline: 1.2962x; 1.2962x over previous
//
#include <hip/hip_runtime.h>
#include <stdint.h>

// ---------------- common types / helpers ----------------
typedef _Float16 f16x8 __attribute__((ext_vector_type(8)));
typedef _Float16 f16x4 __attribute__((ext_vector_type(4)));
typedef float f32x4  __attribute__((ext_vector_type(4)));

__device__ __forceinline__ _Float16 f2h(float f){ return (_Float16)f; }

// Problem constants
#define NB   32
#define NC   512
#define NH   8
#define ND   64
#define NN   1024

// ---------------- prep kernels ----------------
__global__ __launch_bounds__(256) void wt_conv(const float* __restrict__ Wq,
                                               const float* __restrict__ Wk,
                                               const float* __restrict__ Wv,
                                               _Float16* __restrict__ Wt){
  int idx = blockIdx.x * 256 + threadIdx.x;          // 1536*512 = 786432 exact
  int sel = idx >> 18;                               // 262144 per matrix
  const float* W = (sel == 0) ? Wq : (sel == 1) ? Wk : Wv;
  Wt[idx] = f2h(W[idx & 262143]);
}

__global__ __launch_bounds__(256) void transpose_x(const float* __restrict__ x,
                                                   _Float16* __restrict__ xT){
  __shared__ float tile[32][33];
  int n0 = blockIdx.x * 32, c0 = blockIdx.y * 32, b = blockIdx.z;
  int t = threadIdx.x;
  int tn = t & 31, tc = t >> 5;                      // 8 c-rows per pass
#pragma unroll
  for (int k = 0; k < 4; k++)
    tile[tc + 8*k][tn] = x[(b*NC + c0 + tc + 8*k)*NN + n0 + tn];
  __syncthreads();
#pragma unroll
  for (int k = 0; k < 4; k++)
    xT[(b*NN + n0 + tc + 8*k)*NC + c0 + tn] = f2h(tile[tn][tc + 8*k]);
}

__global__ __launch_bounds__(256) void pos_conv(const float* __restrict__ rel_h,
                                                const float* __restrict__ rel_w,
                                                _Float16* __restrict__ pos_t){
  int idx = blockIdx.x * 256 + threadIdx.x;          // 8*1024*64 = 524288 exact
  int d = idx & 63, n = (idx >> 6) & 1023, h = idx >> 16;
  int ww = n >> 5, hh = n & 31;
  float v = rel_h[(h*ND + d)*32 + hh] + rel_w[(h*ND + d)*32 + ww];
  pos_t[idx] = f2h(v);
}

// ---------------- QKV projection GEMM ----------------
// C[o,pix] = sum_c Wt[o,c]*xT[b,pix,c] + bias[o], o in [0,1536) stacked q|k|v.
// Output: q/k pixel-major f16 [b][h][pix][d];  v d-major [b][h][d][pix].
#define ASTR 72      // LDS K-stride in halves (64 + 8 pad) -> 144B
#define TSTR 136     // epilogue tile stride in halves (128 + 8) -> 272B

__global__ __launch_bounds__(256) void proj_gemm(const _Float16* __restrict__ Wt,
                                                 const _Float16* __restrict__ xT,
                                                 const float* __restrict__ bq,
                                                 const float* __restrict__ bk,
                                                 const float* __restrict__ bv,
                                                 _Float16* __restrict__ q_ws,
                                                 _Float16* __restrict__ k_ws,
                                                 _Float16* __restrict__ v_ws){
  __shared__ _Float16 smem[2 * 128 * ASTR];          // 18432 halves = 36864 B
  _Float16* As = smem;                               // [128][ASTR]
  _Float16* Bs = smem + 128 * ASTR;                  // [128][ASTR]

  int mt = blockIdx.x;         // 0..11  (row tile of 1536; 8..11 = v)
  int nt = blockIdx.y;         // 0..7   (pixel tile of 1024)
  int b  = blockIdx.z;
  int t = threadIdx.x, lane = t & 63, w = t >> 6;
  int wm = w >> 1, wn = w & 1;
  int lr = lane & 15, lg = lane >> 4;

  f32x4 acc[4][4];
#pragma unroll
  for (int i = 0; i < 4; i++)
#pragma unroll
    for (int j = 0; j < 4; j++) acc[i][j] = (f32x4)0.f;

  const _Float16* Arow = Wt + mt * 128 * NC;
  const _Float16* Brow = xT + (b * NN + nt * 128) * NC;

  for (int k0 = 0; k0 < NC; k0 += 64){
    __syncthreads();
#pragma unroll
    for (int i = 0; i < 4; i++){
      int lin = t + 256 * i;                          // 0..1023
      int row = lin >> 3, c8 = lin & 7;
      *(f16x8*)(As + row*ASTR + c8*8) = *(const f16x8*)(Arow + row*NC + k0 + c8*8);
      *(f16x8*)(Bs + row*ASTR + c8*8) = *(const f16x8*)(Brow + row*NC + k0 + c8*8);
    }
    __syncthreads();
#pragma unroll
    for (int ks = 0; ks < 2; ks++){
      f16x8 af[4], bfr[4];
#pragma unroll
      for (int mi = 0; mi < 4; mi++)
        af[mi] = *(f16x8*)(As + (wm*64 + mi*16 + lr)*ASTR + ks*32 + lg*8);
#pragma unroll
      for (int nj = 0; nj < 4; nj++)
        bfr[nj] = *(f16x8*)(Bs + (wn*64 + nj*16 + lr)*ASTR + ks*32 + lg*8);
#pragma unroll
      for (int mi = 0; mi < 4; mi++)
#pragma unroll
        for (int nj = 0; nj < 4; nj++)
          acc[mi][nj] = __builtin_amdgcn_mfma_f32_16x16x32_f16(af[mi], bfr[nj], acc[mi][nj], 0, 0, 0);
    }
  }
  __syncthreads();

  if (mt < 8){
    // q/k path: +bias, ->f16, LDS tile [pix][o_loc], coalesced pixel-major store
    _Float16* Ts = smem;                              // 128*136 = 17408 halves
#pragma unroll
    for (int mi = 0; mi < 4; mi++){
      int o0 = wm*64 + mi*16 + 4*lg;
      int og = mt*128 + o0;
      int sel = og >> 9, oo = og & 511;
      const float* bias = (sel == 0) ? bq : bk;
      float b0 = bias[oo], b1 = bias[oo+1], b2 = bias[oo+2], b3 = bias[oo+3];
#pragma unroll
      for (int nj = 0; nj < 4; nj++){
        int pix = wn*64 + nj*16 + lr;
        f16x4 pk;
        pk[0] = f2h(acc[mi][nj][0] + b0);
        pk[1] = f2h(acc[mi][nj][1] + b1);
        pk[2] = f2h(acc[mi][nj][2] + b2);
        pk[3] = f2h(acc[mi][nj][3] + b3);
        *(f16x4*)(Ts + pix*TSTR + o0) = pk;
      }
    }
    __syncthreads();
#pragma unroll
    for (int i = 0; i < 8; i++){
      int lin = t + 256 * i;                          // 0..2047
      int c_o = lin & 15, pix = lin >> 4;
      f16x8 v = *(f16x8*)(Ts + pix*TSTR + c_o*8);
      int og = mt*128 + c_o*8;
      int sel = og >> 9, oo = og & 511;
      int head = oo >> 6, d = oo & 63;
      _Float16* dst = (sel == 0) ? q_ws : k_ws;
      *(f16x8*)(dst + (((b*NH + head)*NN) + nt*128 + pix)*ND + d) = v;
    }
  } else {
    // v path: +bias, ->f16, LDS tile [o_loc][pix], d-major store v_ws[b][h][d][n]
    _Float16* Ts2 = smem;                             // [128][TSTR]
#pragma unroll
    for (int mi = 0; mi < 4; mi++){
      int o0 = wm*64 + mi*16 + 4*lg;
      int vb = (mt - 8)*128 + o0;
      float b0 = bv[vb], b1 = bv[vb+1], b2 = bv[vb+2], b3 = bv[vb+3];
#pragma unroll
      for (int nj = 0; nj < 4; nj++){
        int pix = wn*64 + nj*16 + lr;
        Ts2[(o0+0)*TSTR + pix] = f2h(acc[mi][nj][0] + b0);
        Ts2[(o0+1)*TSTR + pix] = f2h(acc[mi][nj][1] + b1);
        Ts2[(o0+2)*TSTR + pix] = f2h(acc[mi][nj][2] + b2);
        Ts2[(o0+3)*TSTR + pix] = f2h(acc[mi][nj][3] + b3);
      }
    }
    __syncthreads();
#pragma unroll
    for (int i = 0; i < 8; i++){
      int lin = t + 256 * i;                          // 0..2047
      int pix8 = lin & 15, o_loc = lin >> 4;          // 16 pix-chunks x 128 o
      f16x8 v = *(f16x8*)(Ts2 + o_loc*TSTR + pix8*8);
      int vb = (mt - 8)*128 + o_loc;
      int head = vb >> 6, d = vb & 63;
      *(f16x8*)(v_ws + ((b*NH + head)*ND + d)*NN + nt*128 + pix8*8) = v;
    }
  }
}

// ---------------- fused attention (swapped-QK, Q in regs) ----------------
// Block: 128 q-rows x (head, batch). Wave w owns q rows [w*32, w*32+32).
// LDS (halves): Kc[64][136] @0 | Vt[64][72] @8704 | P[128][72] @13312  = 45056 B
#define KSTR 136
#define VSTR 72
#define PSTR 72
#define OSTR 65
#define OFF_VT 8704
#define OFF_P  13312

__global__ __launch_bounds__(256, 3) void attn_kernel(const _Float16* __restrict__ q_ws,
                                                      const _Float16* __restrict__ k_ws,
                                                      const _Float16* __restrict__ v_ws,
                                                      const _Float16* __restrict__ pos_t,
                                                      float* __restrict__ out){
  __shared__ _Float16 smem[22528];                   // 45056 B
  _Float16* Kc = smem;
  _Float16* Vt = smem + OFF_VT;
  _Float16* Pl = smem + OFF_P;

  // XCD-aware swizzle: 8 q-tiles sharing one (b,h)'s K/V -> same XCD L2
  int bid = blockIdx.x;                              // 0..2047
  int sid = (bid & 7) * 256 + (bid >> 3);
  int qt = sid & 7, h = (sid >> 3) & 7, b = sid >> 6;

  int t = threadIdx.x, lane = t & 63, w = t >> 6;
  int lr = lane & 15, lg = lane >> 4;

  const _Float16* qbh = q_ws + (b*NH + h) * NN * ND;
  const _Float16* kbh = k_ws + (b*NH + h) * NN * ND;
  const _Float16* vbh = v_ws + (b*NH + h) * ND * NN; // d-major
  const _Float16* pph = pos_t + h * NN * ND;

  // Q+pos fragments in registers: qreg[qi][ks] = Qc[qt*128+w*32+qi*16+lr][ks*32+lg*8..]
  f16x8 qreg[2][4];
#pragma unroll
  for (int qi = 0; qi < 2; qi++){
    int row = qt*128 + w*32 + qi*16 + lr;
#pragma unroll
    for (int ks = 0; ks < 4; ks++){
      const _Float16* src = (ks < 2) ? (qbh + row*ND + ks*32 + lg*8)
                                     : (pph + row*ND + (ks-2)*32 + lg*8);
      qreg[qi][ks] = *(const f16x8*)src;
    }
  }

  float m_r[2], l_r[2];
  f32x4 oacc[2][4];
#pragma unroll
  for (int qi = 0; qi < 2; qi++){ m_r[qi] = -1e30f; l_r[qi] = 0.f; }
#pragma unroll
  for (int qi = 0; qi < 2; qi++)
#pragma unroll
    for (int dj = 0; dj < 4; dj++) oacc[qi][dj] = (f32x4)0.f;

  for (int n0 = 0; n0 < NN; n0 += 64){
    __syncthreads();
    // stage Kc: row n -> [ k(64) | q(64) ]
#pragma unroll
    for (int i = 0; i < 4; i++){
      int lin = t + 256*i;                           // 0..1023
      int row = lin >> 4, c8 = lin & 15;
      const _Float16* src = (c8 < 8) ? (kbh + (n0 + row)*ND + c8*8)
                                     : (qbh + (n0 + row)*ND + (c8 - 8)*8);
      *(f16x8*)(Kc + row*KSTR + c8*8) = *(const f16x8*)src;
    }
    // stage Vt[d][kk] = V[n0+kk][d] : straight b128 copies from d-major v_ws
#pragma unroll
    for (int i = 0; i < 2; i++){
      int lin = t + 256*i;                           // 0..511
      int d = lin >> 3, ch = lin & 7;
      *(f16x8*)(Vt + d*VSTR + ch*8) = *(const f16x8*)(vbh + d*NN + n0 + ch*8);
    }
    __syncthreads();

    // S^T = Kc . Qreg : sacc[kt][qi], C row = key = 4*lg+r, col = q = lr
    f32x4 sacc[4][2];
#pragma unroll
    for (int kt = 0; kt < 4; kt++)
#pragma unroll
      for (int qi = 0; qi < 2; qi++) sacc[kt][qi] = (f32x4)0.f;
#pragma unroll
    for (int ks = 0; ks < 4; ks++){
      f16x8 kf[4];
#pragma unroll
      for (int kt = 0; kt < 4; kt++)
        kf[kt] = *(f16x8*)(Kc + (kt*16 + lr)*KSTR + ks*32 + lg*8);
#pragma unroll
      for (int kt = 0; kt < 4; kt++)
#pragma unroll
        for (int qi = 0; qi < 2; qi++)
          sacc[kt][qi] = __builtin_amdgcn_mfma_f32_16x16x32_f16(kf[kt], qreg[qi][ks], sacc[kt][qi], 0, 0, 0);
    }

    // online softmax: lane owns q-row (qi*16+lr); keys in-lane (kt,r) + lg groups
#pragma unroll
    for (int qi = 0; qi < 2; qi++){
      float mx = sacc[0][qi][0];
#pragma unroll
      for (int kt = 0; kt < 4; kt++)
#pragma unroll
        for (int r = 0; r < 4; r++) mx = fmaxf(mx, sacc[kt][qi][r]);
      mx = fmaxf(mx, __shfl_xor(mx, 16));
      mx = fmaxf(mx, __shfl_xor(mx, 32));
      float mn = fmaxf(m_r[qi], mx);
      float cr = __expf(m_r[qi] - mn);
      m_r[qi] = mn;
      float ts = 0.f;
#pragma unroll
      for (int kt = 0; kt < 4; kt++){
        float p0 = __expf(sacc[kt][qi][0] - mn);
        float p1 = __expf(sacc[kt][qi][1] - mn);
        float p2 = __expf(sacc[kt][qi][2] - mn);
        float p3 = __expf(sacc[kt][qi][3] - mn);
        ts += (p0 + p1) + (p2 + p3);
        f16x4 pk;
        pk[0] = f2h(p0); pk[1] = f2h(p1); pk[2] = f2h(p2); pk[3] = f2h(p3);
        // P[q][k]: row = w*32+qi*16+lr, k = kt*16 + lg*4 (+0..3), packed b64 write
        *(f16x4*)(Pl + (w*32 + qi*16 + lr)*PSTR + kt*16 + lg*4) = pk;
      }
      ts += __shfl_xor(ts, 16);
      ts += __shfl_xor(ts, 32);
      l_r[qi] = l_r[qi]*cr + ts;
      // rescale oacc rows q = 4*lg+r with that row's cr (held at lane lr = 4*lg+r)
#pragma unroll
      for (int r = 0; r < 4; r++){
        float crow = __shfl(cr, 4*lg + r);
#pragma unroll
        for (int dj = 0; dj < 4; dj++) oacc[qi][dj][r] *= crow;
      }
    }

    // PV: O[q][d] += P . Vt  (wave-private P rows -> no barrier, lgkmcnt only)
#pragma unroll
    for (int ks = 0; ks < 2; ks++){
      f16x8 pf[2], vf[4];
#pragma unroll
      for (int qi = 0; qi < 2; qi++)
        pf[qi] = *(f16x8*)(Pl + (w*32 + qi*16 + lr)*PSTR + ks*32 + lg*8);
#pragma unroll
      for (int dj = 0; dj < 4; dj++)
        vf[dj] = *(f16x8*)(Vt + (dj*16 + lr)*VSTR + ks*32 + lg*8);
#pragma unroll
      for (int qi = 0; qi < 2; qi++)
#pragma unroll
        for (int dj = 0; dj < 4; dj++)
          oacc[qi][dj] = __builtin_amdgcn_mfma_f32_16x16x32_f16(pf[qi], vf[dj], oacc[qi][dj], 0, 0, 0);
    }
  }

  __syncthreads();
  float* Ot = (float*)smem;                          // [128][OSTR] fp32 = 33280 B
#pragma unroll
  for (int qi = 0; qi < 2; qi++){
    float iv = 1.f / l_r[qi];
#pragma unroll
    for (int r = 0; r < 4; r++){
      float invr = __shfl(iv, 4*lg + r);
#pragma unroll
      for (int dj = 0; dj < 4; dj++)
        Ot[(w*32 + qi*16 + 4*lg + r)*OSTR + dj*16 + lr] = oacc[qi][dj][r] * invr;
    }
  }
  __syncthreads();

  // coalesced store: out[b][h*64+d][qt*128 + j]
#pragma unroll
  for (int i = 0; i < 8; i++){
    int lin = t + 256*i;                             // 0..2047
    int jc = lin & 31, d = lin >> 5;
    float4 v;
    v.x = Ot[(jc*4 + 0)*OSTR + d];
    v.y = Ot[(jc*4 + 1)*OSTR + d];
    v.z = Ot[(jc*4 + 2)*OSTR + d];
    v.w = Ot[(jc*4 + 3)*OSTR + d];
    *(float4*)(out + (b*NC + h*ND + d)*NN + qt*128 + jc*4) = v;
  }
}

// ---------------- LayerNorm + residual ----------------
__global__ __launch_bounds__(256) void ln_partial(const float* __restrict__ out,
                                                  float* __restrict__ red){
  int i = blockIdx.x, b = blockIdx.y, t = threadIdx.x;
  const float4* p = (const float4*)(out + b*524288 + i*65536);
  float s = 0.f, sq = 0.f;
  for (int k = t; k < 16384; k += 256){
    float4 v = p[k];
    s  += v.x + v.y + v.z + v.w;
    sq += v.x*v.x + v.y*v.y + v.z*v.z + v.w*v.w;
  }
  for (int off = 32; off; off >>= 1){ s += __shfl_down(s, off); sq += __shfl_down(sq, off); }
  __shared__ float ls[8];
  int w = t >> 6, lane = t & 63;
  if (lane == 0){ ls[w*2] = s; ls[w*2 + 1] = sq; }
  __syncthreads();
  if (t == 0){
    red[(b*8 + i)*2]     = ls[0] + ls[2] + ls[4] + ls[6];
    red[(b*8 + i)*2 + 1] = ls[1] + ls[3] + ls[5] + ls[7];
  }
}

__global__ void ln_stats(const float* __restrict__ red, float* __restrict__ stats){
  int b = threadIdx.x;
  if (b < 32){
    float s = 0.f, sq = 0.f;
    for (int j = 0; j < 8; j++){ s += red[(b*8 + j)*2]; sq += red[(b*8 + j)*2 + 1]; }
    float mu  = s * (1.f / 524288.f);
    float var = sq * (1.f / 524288.f) - mu*mu;
    stats[b*2] = mu;
    stats[b*2 + 1] = rsqrtf(var + 1e-5f);
  }
}

__global__ __launch_bounds__(256) void ln_apply(const float* __restrict__ x,
                                                const float* __restrict__ lw,
                                                const float* __restrict__ lb,
                                                const float* __restrict__ stats,
                                                float* __restrict__ out){
  int tid = blockIdx.x*256 + threadIdx.x;
  for (int i4 = tid; i4 < 4194304; i4 += 524288){
    int b = i4 >> 17;                                // 131072 float4 per batch
    int r4 = i4 & 131071;
    float mu = stats[b*2], rs = stats[b*2 + 1];
    float4 o  = ((const float4*)out)[i4];
    float4 xv = ((const float4*)x)[i4];
    float4 ww = ((const float4*)lw)[r4];
    float4 bb = ((const float4*)lb)[r4];
    o.x = (o.x - mu)*rs*ww.x + bb.x + xv.x;
    o.y = (o.y - mu)*rs*ww.y + bb.y + xv.y;
    o.z = (o.z - mu)*rs*ww.z + bb.z + xv.z;
    o.w = (o.w - mu)*rs*ww.w + bb.w + xv.w;
    ((float4*)out)[i4] = o;
  }
}

// ---------------- launch ----------------
extern "C" void kernel_launch(void* const* d_in, const int* in_sizes, int n_in,
                              void* d_out, int out_size, void* d_ws, size_t ws_size,
                              hipStream_t stream){
  (void)in_sizes; (void)n_in; (void)out_size; (void)ws_size;
  const float* x    = (const float*)d_in[0];
  const float* Wq   = (const float*)d_in[1];
  const float* bq   = (const float*)d_in[2];
  const float* Wk   = (const float*)d_in[3];
  const float* bk   = (const float*)d_in[4];
  const float* Wv   = (const float*)d_in[5];
  const float* bv   = (const float*)d_in[6];
  const float* relh = (const float*)d_in[7];
  const float* relw = (const float*)d_in[8];
  const float* lnw  = (const float*)d_in[9];
  const float* lnb  = (const float*)d_in[10];
  float* out = (float*)d_out;
  char* ws = (char*)d_ws;

  _Float16* q_ws  = (_Float16*)(ws);
  _Float16* k_ws  = (_Float16*)(ws + 33554432);
  _Float16* v_ws  = (_Float16*)(ws + 67108864);   // d-major [b][h][d][n]
  _Float16* xT    = (_Float16*)(ws + 100663296);
  _Float16* Wt    = (_Float16*)(ws + 134217728);
  _Float16* pos_t = (_Float16*)(ws + 135790592);
  float* red   = (float*)(ws + 136839168);
  float* stats = red + 512;

  wt_conv    <<<3072, 256, 0, stream>>>(Wq, Wk, Wv, Wt);
  transpose_x<<<dim3(32, 16, 32), 256, 0, stream>>>(x, xT);
  pos_conv   <<<2048, 256, 0, stream>>>(relh, relw, pos_t);
  proj_gemm  <<<dim3(12, 8, 32), 256, 0, stream>>>(Wt, xT, bq, bk, bv, q_ws, k_ws, v_ws);
  attn_kernel<<<2048, 256, 0, stream>>>(q_ws, k_ws, v_ws, pos_t, out);
  ln_partial <<<dim3(8, 32), 256, 0, stream>>>(out, red);
  ln_stats   <<<1, 64, 0, stream>>>(red, stats);
  ln_apply   <<<2048, 256, 0, stream>>>(x, lnw, lnb, stats, out);
}